// Round 4
// baseline (333.383 us; speedup 1.0000x reference)
//
#include <hip/hip_runtime.h>

#define Bn 4
#define Sn 2048
#define Dn 1024
#define Hn 16
#define HDn 64

typedef unsigned short u16;
typedef unsigned int u32;
typedef __bf16 bf16x8 __attribute__((ext_vector_type(8)));
typedef float f32x4 __attribute__((ext_vector_type(4)));

// pack two f32 -> two bf16 (RNE), elem a in low half
__device__ __forceinline__ u32 pack_rne(float a, float b) {
    u32 ua = __float_as_uint(a); ua += 0x7fffu + ((ua >> 16) & 1u);
    u32 ub = __float_as_uint(b); ub += 0x7fffu + ((ub >> 16) & 1u);
    return __builtin_amdgcn_perm(ub, ua, 0x07060302u);
}
// truncating pack (1 instr) — bias cancels because l is summed from truncated P
__device__ __forceinline__ u32 pack_trunc(float a, float b) {
    return __builtin_amdgcn_perm(__float_as_uint(b), __float_as_uint(a), 0x07060302u);
}

__device__ __forceinline__ void async_copy16(const u16* g, u16* l) {
    __builtin_amdgcn_global_load_lds(
        (__attribute__((address_space(1))) void*)(g),
        (__attribute__((address_space(3))) void*)(l), 16, 0, 0);
}

// ---------------- fp32 -> bf16 convert, multi-tensor (slice = blockIdx.y) ----
struct CvtArgs {
    const float* in[7];
    u16* out[7];
    int n4[7];
};
__global__ __launch_bounds__(256) void cvt_multi(CvtArgs a) {
    int s = blockIdx.y;
    const float4* in4 = (const float4*)a.in[s];
    uint2* out2 = (uint2*)a.out[s];
    int n4 = a.n4[s];
    int i = blockIdx.x * blockDim.x + threadIdx.x;
    int stride = gridDim.x * blockDim.x;
    for (; i < n4; i += stride) {
        float4 v = in4[i];
        out2[i] = make_uint2(pack_rne(v.x, v.y), pack_rne(v.z, v.w));
    }
}

// ---------------- bf16 GEMM: C = scale * A·Bwᵀ,  M=8192 N=K=1024 -------------
// BK=64, XOR column-group swizzle (global-side, preserves global_load_lds
// lane-contiguity): LDS slot [r][g*8..] holds global cols (g^(r&7))*8..
// mode 1: bf16 out, head-split (B,H,S,HD), swapped operands -> uint2 stores (Q,K)
// mode 2: fp32 out, flat, swapped operands -> float4 stores (O projection)
// mode 3: bf16 out, head-split transposed (B,H,HD,S), unswapped (V)
struct GemmArgs {
    const u16* A[3];
    const u16* Bw[3];
    void* C[3];
    float scale[3];
    int mode[3];
};
__global__ __launch_bounds__(256) void gemm_bf16(GemmArgs g, int nz) {
    __shared__ alignas(16) u16 As[128 * 64];
    __shared__ alignas(16) u16 Bs[128 * 64];
    u32 id = blockIdx.x;
    int z = id % nz;
    u32 r2 = id / nz;                 // z-interleaved: all slices co-resident
    int row0 = (int)(r2 >> 3) * 128;  // 64 row-blocks
    int col0 = (int)(r2 & 7) * 128;   // 8 col-blocks (adjacent ids share A rows)

    const u16* A = g.A[z];
    const u16* Bw = g.Bw[z];
    void* Cout = g.C[z];
    float scale = g.scale[z];
    int mode = g.mode[z];

    int t = threadIdx.x;
    int w = t >> 6, lane = t & 63;
    int lane15 = lane & 15, quad = lane >> 4;
    int wr = w >> 1, wc = w & 1;
    int sr = t >> 3, sg = t & 7;      // staging: row-in-pass, slot group

    bool swapped = (mode != 3);
    const u16* PA = swapped ? Bs : As;
    const u16* PB = swapped ? As : Bs;
    int abase = swapped ? wc * 64 : wr * 64;
    int bbase = swapped ? wr * 64 : wc * 64;

    f32x4 acc[4][4];
#pragma unroll
    for (int mt = 0; mt < 4; ++mt)
#pragma unroll
        for (int nt = 0; nt < 4; ++nt)
            acc[mt][nt] = f32x4{0.f, 0.f, 0.f, 0.f};

    for (int k0 = 0; k0 < 1024; k0 += 64) {
        __syncthreads();
#pragma unroll
        for (int i = 0; i < 4; ++i) {
            int r = i * 32 + sr;
            int gc = ((sg ^ (r & 7)) << 3);   // swizzled global col
            const u16* ga = A + (size_t)(row0 + r) * 1024 + k0 + gc;
            const u16* gb = Bw + (size_t)(col0 + r) * 1024 + k0 + gc;
            async_copy16(ga, &As[i * 2048 + w * 512]);
            async_copy16(gb, &Bs[i * 2048 + w * 512]);
        }
        __syncthreads();

#pragma unroll
        for (int kc = 0; kc < 2; ++kc) {
            bf16x8 af[4], bf[4];
#pragma unroll
            for (int mt = 0; mt < 4; ++mt) {
                int r = abase + mt * 16 + lane15;
                af[mt] = *(const bf16x8*)&PA[r * 64 + (((kc * 4 + quad) ^ (r & 7)) << 3)];
            }
#pragma unroll
            for (int nt = 0; nt < 4; ++nt) {
                int r = bbase + nt * 16 + lane15;
                bf[nt] = *(const bf16x8*)&PB[r * 64 + (((kc * 4 + quad) ^ (r & 7)) << 3)];
            }
#pragma unroll
            for (int mt = 0; mt < 4; ++mt)
#pragma unroll
                for (int nt = 0; nt < 4; ++nt)
                    acc[mt][nt] = __builtin_amdgcn_mfma_f32_16x16x32_bf16(
                        af[mt], bf[nt], acc[mt][nt], 0, 0, 0);
        }
    }

#pragma unroll
    for (int mt = 0; mt < 4; ++mt)
#pragma unroll
        for (int nt = 0; nt < 4; ++nt) {
            if (mode == 1) {
                // rows (quad*4+reg) = feature, cols (lane15) = token
                int f0 = col0 + wc * 64 + mt * 16 + quad * 4;
                int tok = row0 + wr * 64 + nt * 16 + lane15;
                int bb = tok >> 11, ss = tok & 2047;
                int hh = f0 >> 6, dd = f0 & 63;
                u32 w0 = pack_rne(acc[mt][nt][0] * scale, acc[mt][nt][1] * scale);
                u32 w1 = pack_rne(acc[mt][nt][2] * scale, acc[mt][nt][3] * scale);
                u16* p = (u16*)Cout + (((size_t)bb * Hn + hh) * Sn + ss) * HDn + dd;
                *(uint2*)p = make_uint2(w0, w1);
            } else if (mode == 2) {
                // swapped: feature quartet consecutive -> float4 store
                int f0 = col0 + wc * 64 + mt * 16 + quad * 4;
                int tok = row0 + wr * 64 + nt * 16 + lane15;
                float4 o = make_float4(acc[mt][nt][0] * scale, acc[mt][nt][1] * scale,
                                       acc[mt][nt][2] * scale, acc[mt][nt][3] * scale);
                *(float4*)((float*)Cout + (size_t)tok * 1024 + f0) = o;
            } else {
                // mode 3 unswapped: rows = token quartet; write (B,H,HD,S)
                int n = col0 + wc * 64 + nt * 16 + lane15;
                int m0 = row0 + wr * 64 + mt * 16 + quad * 4;
                int bb = m0 >> 11, ss = m0 & 2047;
                int hh = n >> 6, dd = n & 63;
                u32 w0 = pack_rne(acc[mt][nt][0] * scale, acc[mt][nt][1] * scale);
                u32 w1 = pack_rne(acc[mt][nt][2] * scale, acc[mt][nt][3] * scale);
                u16* p = (u16*)Cout + (((size_t)bb * Hn + hh) * HDn + dd) * Sn + ss;
                *(uint2*)p = make_uint2(w0, w1);
            }
        }
}

// ---------------- flash attention, transposed-S, no-max softmax --------------
__global__ __launch_bounds__(256, 4) void attn_kernel(const u16* __restrict__ Qh,
                                                      const u16* __restrict__ Kh,
                                                      const u16* __restrict__ Vtg,
                                                      const int* __restrict__ valid_lens,
                                                      u16* __restrict__ O) {
    __shared__ alignas(16) u16 Ks[64 * 72];   // [key][d]
    __shared__ alignas(16) u16 Vt[64 * 72];   // [d][swz(key)]

    int t = threadIdx.x;
    int w = t >> 6, lane = t & 63;
    int lane15 = lane & 15, quad = lane >> 4;

    u32 raw = blockIdx.x;
    int qt = raw >> 6;
    int h = (raw >> 2) & 15;
    int b = (raw & 3) ^ ((raw >> 8) & 3);
    int bh = b * Hn + h;
    int q0 = qt * 128;
    int vl = valid_lens[b];
    int ntiles = (vl + 63) >> 6;

    const u16* Qb = Qh + (size_t)bh * (Sn * HDn);
    const u16* Kb = Kh + (size_t)bh * (Sn * HDn);
    const u16* Vb = Vtg + (size_t)bh * (HDn * Sn);

    int sr = t >> 3;
    int sc8 = (t & 7) * 8;
    int va = t & 7;
    int vcb = ((va & 4) << 3) | ((va & 1) << 4) | ((va & 2) << 1);  // key swizzle

    bf16x8 qf[2][2];
#pragma unroll
    for (int nt = 0; nt < 2; ++nt)
#pragma unroll
        for (int kc = 0; kc < 2; ++kc)
            qf[nt][kc] = *(const bf16x8*)(Qb + (size_t)(q0 + w * 32 + nt * 16 + lane15) * HDn +
                                          kc * 32 + quad * 8);

    f32x4 oacc[4][2], lacc[2];
#pragma unroll
    for (int mt = 0; mt < 4; ++mt)
#pragma unroll
        for (int nt = 0; nt < 2; ++nt)
            oacc[mt][nt] = f32x4{0.f, 0.f, 0.f, 0.f};
    lacc[0] = f32x4{0.f, 0.f, 0.f, 0.f};
    lacc[1] = f32x4{0.f, 0.f, 0.f, 0.f};

    union { u32 u[4]; bf16x8 v; } ones;
    ones.u[0] = ones.u[1] = ones.u[2] = ones.u[3] = 0x3F803F80u;

    uint4 kpre[2], vpre[2];
#pragma unroll
    for (int p = 0; p < 2; ++p) {
        kpre[p] = *(const uint4*)(Kb + (size_t)(p * 32 + sr) * HDn + sc8);
        vpre[p] = *(const uint4*)(Vb + (size_t)(p * 32 + sr) * Sn + sc8);
    }

    for (int kt = 0; kt < ntiles; ++kt) {
        int kbase = kt * 64;
        __syncthreads();
#pragma unroll
        for (int p = 0; p < 2; ++p) {
            *(uint4*)&Ks[(p * 32 + sr) * 72 + sc8] = kpre[p];
            int drow = (p * 32 + sr) * 72;
            *(uint2*)&Vt[drow + vcb] = make_uint2(vpre[p].x, vpre[p].y);
            *(uint2*)&Vt[drow + vcb + 8] = make_uint2(vpre[p].z, vpre[p].w);
        }
        __syncthreads();

        int nkb = (kt + 1 < ntiles) ? kbase + 64 : kbase;
#pragma unroll
        for (int p = 0; p < 2; ++p) {
            kpre[p] = *(const uint4*)(Kb + (size_t)(nkb + p * 32 + sr) * HDn + sc8);
            vpre[p] = *(const uint4*)(Vb + (size_t)(p * 32 + sr) * Sn + nkb + sc8);
        }

        // Sᵀ = K·Qᵀ
        f32x4 sc[4][2];
#pragma unroll
        for (int mt = 0; mt < 4; ++mt) {
            bf16x8 kf0 = *(const bf16x8*)&Ks[(mt * 16 + lane15) * 72 + quad * 8];
            bf16x8 kf1 = *(const bf16x8*)&Ks[(mt * 16 + lane15) * 72 + 32 + quad * 8];
#pragma unroll
            for (int nt = 0; nt < 2; ++nt) {
                f32x4 s = f32x4{0.f, 0.f, 0.f, 0.f};
                s = __builtin_amdgcn_mfma_f32_16x16x32_bf16(kf0, qf[nt][0], s, 0, 0, 0);
                s = __builtin_amdgcn_mfma_f32_16x16x32_bf16(kf1, qf[nt][1], s, 0, 0, 0);
                sc[mt][nt] = s;
            }
        }

        if (kbase + 64 > vl) {
#pragma unroll
            for (int mt = 0; mt < 4; ++mt)
#pragma unroll
                for (int reg = 0; reg < 4; ++reg) {
                    int key = kbase + mt * 16 + quad * 4 + reg;
                    if (key >= vl) {
                        sc[mt][0][reg] = -1e30f;
                        sc[mt][1][reg] = -1e30f;
                    }
                }
        }

#pragma unroll
        for (int mt = 0; mt < 4; ++mt)
#pragma unroll
            for (int nt = 0; nt < 2; ++nt)
#pragma unroll
                for (int reg = 0; reg < 4; ++reg)
                    sc[mt][nt][reg] = __builtin_amdgcn_exp2f(sc[mt][nt][reg]);

        union { u32 u[4]; bf16x8 v; } pv[2][2];
#pragma unroll
        for (int nt = 0; nt < 2; ++nt) {
            pv[nt][0].u[0] = pack_trunc(sc[0][nt][0], sc[0][nt][1]);
            pv[nt][0].u[1] = pack_trunc(sc[0][nt][2], sc[0][nt][3]);
            pv[nt][0].u[2] = pack_trunc(sc[1][nt][0], sc[1][nt][1]);
            pv[nt][0].u[3] = pack_trunc(sc[1][nt][2], sc[1][nt][3]);
            pv[nt][1].u[0] = pack_trunc(sc[2][nt][0], sc[2][nt][1]);
            pv[nt][1].u[1] = pack_trunc(sc[2][nt][2], sc[2][nt][3]);
            pv[nt][1].u[2] = pack_trunc(sc[3][nt][0], sc[3][nt][1]);
            pv[nt][1].u[3] = pack_trunc(sc[3][nt][2], sc[3][nt][3]);
            lacc[nt] = __builtin_amdgcn_mfma_f32_16x16x32_bf16(
                ones.v, pv[nt][0].v, lacc[nt], 0, 0, 0);
            lacc[nt] = __builtin_amdgcn_mfma_f32_16x16x32_bf16(
                ones.v, pv[nt][1].v, lacc[nt], 0, 0, 0);
        }

#pragma unroll
        for (int mt = 0; mt < 4; ++mt) {
            bf16x8 vf0 = *(const bf16x8*)&Vt[(mt * 16 + lane15) * 72 + quad * 8];
            bf16x8 vf1 = *(const bf16x8*)&Vt[(mt * 16 + lane15) * 72 + 32 + quad * 8];
#pragma unroll
            for (int nt = 0; nt < 2; ++nt) {
                oacc[mt][nt] = __builtin_amdgcn_mfma_f32_16x16x32_bf16(
                    vf0, pv[nt][0].v, oacc[mt][nt], 0, 0, 0);
                oacc[mt][nt] = __builtin_amdgcn_mfma_f32_16x16x32_bf16(
                    vf1, pv[nt][1].v, oacc[mt][nt], 0, 0, 0);
            }
        }
    }

    float rl[2];
    rl[0] = __builtin_amdgcn_rcpf(lacc[0][0]);
    rl[1] = __builtin_amdgcn_rcpf(lacc[1][0]);
#pragma unroll
    for (int mt = 0; mt < 4; ++mt)
#pragma unroll
        for (int nt = 0; nt < 2; ++nt) {
            int q = q0 + w * 32 + nt * 16 + lane15;
            int d = h * HDn + mt * 16 + quad * 4;
            u32 w0 = pack_rne(oacc[mt][nt][0] * rl[nt], oacc[mt][nt][1] * rl[nt]);
            u32 w1 = pack_rne(oacc[mt][nt][2] * rl[nt], oacc[mt][nt][3] * rl[nt]);
            *(uint2*)&O[((size_t)b * Sn + q) * Dn + d] = make_uint2(w0, w1);
        }
}

extern "C" void kernel_launch(void* const* d_in, const int* in_sizes, int n_in,
                              void* d_out, int out_size, void* d_ws, size_t ws_size,
                              hipStream_t stream) {
    const float* q  = (const float*)d_in[0];
    const float* k  = (const float*)d_in[1];
    const float* v  = (const float*)d_in[2];
    const int*   vl = (const int*)d_in[3];
    const float* Wq = (const float*)d_in[4];
    const float* Wk = (const float*)d_in[5];
    const float* Wv = (const float*)d_in[6];
    const float* Wo = (const float*)d_in[7];

    u16* ws = (u16*)d_ws;
    const size_t NE = (size_t)Bn * Sn * Dn;
    const size_t NW = (size_t)Dn * Dn;
    const float qscale = 0.125f * 1.44269504f;

    if (ws_size >= (6 * NE + 4 * NW) * 2) {
        u16* Qh  = ws;
        u16* Kh  = Qh + NE;
        u16* Vh  = Kh + NE;      // (B,H,HD,S)
        u16* Xq  = Vh + NE;
        u16* Xk  = Xq + NE;
        u16* Xv  = Xk + NE;
        u16* Wqb = Xv + NE;
        u16* Wkb = Wqb + NW;
        u16* Wvb = Wkb + NW;
        u16* Wob = Wvb + NW;
        u16* Ob  = Xq;           // reuse after projections

        CvtArgs ca;
        ca.in[0] = q;  ca.out[0] = Xq;  ca.n4[0] = (int)(NE / 4);
        ca.in[1] = k;  ca.out[1] = Xk;  ca.n4[1] = (int)(NE / 4);
        ca.in[2] = v;  ca.out[2] = Xv;  ca.n4[2] = (int)(NE / 4);
        ca.in[3] = Wq; ca.out[3] = Wqb; ca.n4[3] = (int)(NW / 4);
        ca.in[4] = Wk; ca.out[4] = Wkb; ca.n4[4] = (int)(NW / 4);
        ca.in[5] = Wv; ca.out[5] = Wvb; ca.n4[5] = (int)(NW / 4);
        ca.in[6] = Wo; ca.out[6] = Wob; ca.n4[6] = (int)(NW / 4);
        cvt_multi<<<dim3(512, 7), 256, 0, stream>>>(ca);

        GemmArgs gp;
        gp.A[0] = Xq; gp.Bw[0] = Wqb; gp.C[0] = Qh; gp.scale[0] = qscale; gp.mode[0] = 1;
        gp.A[1] = Xk; gp.Bw[1] = Wkb; gp.C[1] = Kh; gp.scale[1] = 1.0f;   gp.mode[1] = 1;
        gp.A[2] = Xv; gp.Bw[2] = Wvb; gp.C[2] = Vh; gp.scale[2] = 1.0f;   gp.mode[2] = 3;
        gemm_bf16<<<dim3(512 * 3), 256, 0, stream>>>(gp, 3);

        attn_kernel<<<dim3(1024), 256, 0, stream>>>(Qh, Kh, Vh, vl, Ob);

        GemmArgs go;
        for (int i = 0; i < 3; ++i) {
            go.A[i] = Ob; go.Bw[i] = Wob; go.C[i] = d_out;
            go.scale[i] = 1.0f; go.mode[i] = 2;
        }
        gemm_bf16<<<dim3(512), 256, 0, stream>>>(go, 1);
    } else {
        u16* Qh  = ws;
        u16* Kh  = Qh + NE;
        u16* Vh  = Kh + NE;
        u16* Xb  = Vh + NE;
        u16* Wqb = Xb + NE;
        u16* Wkb = Wqb + NW;
        u16* Wvb = Wkb + NW;
        u16* Wob = Wvb + NW;
        u16* Ob  = Wob + NW;

        CvtArgs cw;
        cw.in[0] = Wq; cw.out[0] = Wqb; cw.n4[0] = (int)(NW / 4);
        cw.in[1] = Wk; cw.out[1] = Wkb; cw.n4[1] = (int)(NW / 4);
        cw.in[2] = Wv; cw.out[2] = Wvb; cw.n4[2] = (int)(NW / 4);
        cw.in[3] = Wo; cw.out[3] = Wob; cw.n4[3] = (int)(NW / 4);
        for (int i = 4; i < 7; ++i) { cw.in[i] = Wq; cw.out[i] = Wqb; cw.n4[i] = 0; }
        cvt_multi<<<dim3(512, 4), 256, 0, stream>>>(cw);

        const float* xs[3] = {q, k, v};
        u16* outs[3] = {Qh, Kh, Vh};
        const u16* wbs[3] = {Wqb, Wkb, Wvb};
        float scs[3] = {qscale, 1.0f, 1.0f};
        int mds[3] = {1, 1, 3};
        for (int i = 0; i < 3; ++i) {
            CvtArgs cx;
            cx.in[0] = xs[i]; cx.out[0] = Xb; cx.n4[0] = (int)(NE / 4);
            for (int j = 1; j < 7; ++j) { cx.in[j] = xs[i]; cx.out[j] = Xb; cx.n4[j] = 0; }
            cvt_multi<<<dim3(512, 1), 256, 0, stream>>>(cx);
            GemmArgs gp;
            for (int j = 0; j < 3; ++j) {
                gp.A[j] = Xb; gp.Bw[j] = wbs[i]; gp.C[j] = outs[i];
                gp.scale[j] = scs[i]; gp.mode[j] = mds[i];
            }
            gemm_bf16<<<dim3(512), 256, 0, stream>>>(gp, 1);
        }

        attn_kernel<<<dim3(1024), 256, 0, stream>>>(Qh, Kh, Vh, vl, Ob);

        GemmArgs go;
        for (int j = 0; j < 3; ++j) {
            go.A[j] = Ob; go.Bw[j] = Wob; go.C[j] = d_out;
            go.scale[j] = 1.0f; go.mode[j] = 2;
        }
        gemm_bf16<<<dim3(512), 256, 0, stream>>>(go, 1);
    }
}

// Round 5
// 312.057 us; speedup vs baseline: 1.0683x; 1.0683x over previous
//
#include <hip/hip_runtime.h>

#define Bn 4
#define Sn 2048
#define Dn 1024
#define Hn 16
#define HDn 64

typedef unsigned short u16;
typedef unsigned int u32;
typedef __bf16 bf16x8 __attribute__((ext_vector_type(8)));
typedef float f32x4 __attribute__((ext_vector_type(4)));

// pack two f32 -> two bf16 (RNE), elem a in low half
__device__ __forceinline__ u32 pack_rne(float a, float b) {
    u32 ua = __float_as_uint(a); ua += 0x7fffu + ((ua >> 16) & 1u);
    u32 ub = __float_as_uint(b); ub += 0x7fffu + ((ub >> 16) & 1u);
    return __builtin_amdgcn_perm(ub, ua, 0x07060302u);
}
// truncating pack (1 instr) — bias cancels because l is summed from truncated P
__device__ __forceinline__ u32 pack_trunc(float a, float b) {
    return __builtin_amdgcn_perm(__float_as_uint(b), __float_as_uint(a), 0x07060302u);
}

__device__ __forceinline__ void async_copy16(const u16* g, u16* l) {
    __builtin_amdgcn_global_load_lds(
        (__attribute__((address_space(1))) void*)(g),
        (__attribute__((address_space(3))) void*)(l), 16, 0, 0);
}

// ---------------- fp32 -> bf16 convert, multi-tensor (slice = blockIdx.y) ----
struct CvtArgs {
    const float* in[7];
    u16* out[7];
    int n4[7];
};
__global__ __launch_bounds__(256) void cvt_multi(CvtArgs a) {
    int s = blockIdx.y;
    const float4* in4 = (const float4*)a.in[s];
    uint2* out2 = (uint2*)a.out[s];
    int n4 = a.n4[s];
    int i = blockIdx.x * blockDim.x + threadIdx.x;
    int stride = gridDim.x * blockDim.x;
    for (; i < n4; i += stride) {
        float4 v = in4[i];
        out2[i] = make_uint2(pack_rne(v.x, v.y), pack_rne(v.z, v.w));
    }
}

// ---------------- bf16 GEMM: C = scale * A·Bwᵀ,  M=8192 N=K=1024 -------------
// BK=64, XOR column-group swizzle (global-side; preserves global_load_lds
// lane-contiguity): LDS slot [r][g*8..] holds global cols (g^(r&7))*8..
// XCD-aware mapping: id = xcd + 8*(col + 8*(z + NZ*rg)); rowtile = rg*8 + xcd.
// Each XCD streams one 256KB A-tile + one 2MB weight (L2-resident), so A and B
// are fetched ~once per XCD instead of ~4x.
// mode 1: bf16 out, head-split (B,H,S,HD), swapped operands -> uint2 stores (Q,K)
// mode 2: fp32 out, flat, swapped operands -> float4 stores (O projection)
// mode 3: bf16 out, head-split transposed (B,H,HD,S), unswapped (V)
struct GemmArgs {
    const u16* A[3];
    const u16* Bw[3];
    void* C[3];
    float scale[3];
    int mode[3];
};
template <int NZ>
__global__ __launch_bounds__(256, 3) void gemm_bf16(GemmArgs g) {
    __shared__ alignas(16) u16 As[128 * 64];
    __shared__ alignas(16) u16 Bs[128 * 64];
    u32 id = blockIdx.x;
    int xcd = id & 7;
    u32 s = id >> 3;
    int col0 = (int)(s & 7) * 128;
    u32 t2 = s >> 3;
    int z = (int)(t2 % NZ);
    int rg = (int)(t2 / NZ);
    int row0 = (rg * 8 + xcd) * 128;

    const u16* A = g.A[z];
    const u16* Bw = g.Bw[z];
    void* Cout = g.C[z];
    float scale = g.scale[z];
    int mode = g.mode[z];

    int t = threadIdx.x;
    int w = t >> 6, lane = t & 63;
    int lane15 = lane & 15, quad = lane >> 4;
    int wr = w >> 1, wc = w & 1;
    int sr = t >> 3, sg = t & 7;      // staging: row-in-pass, slot group

    bool swapped = (mode != 3);
    const u16* PA = swapped ? Bs : As;
    const u16* PB = swapped ? As : Bs;
    int abase = swapped ? wc * 64 : wr * 64;
    int bbase = swapped ? wr * 64 : wc * 64;

    f32x4 acc[4][4];
#pragma unroll
    for (int mt = 0; mt < 4; ++mt)
#pragma unroll
        for (int nt = 0; nt < 4; ++nt)
            acc[mt][nt] = f32x4{0.f, 0.f, 0.f, 0.f};

    for (int k0 = 0; k0 < 1024; k0 += 64) {
        __syncthreads();
#pragma unroll
        for (int i = 0; i < 4; ++i) {
            int r = i * 32 + sr;
            int gc = ((sg ^ (r & 7)) << 3);   // swizzled global col
            const u16* ga = A + (size_t)(row0 + r) * 1024 + k0 + gc;
            const u16* gb = Bw + (size_t)(col0 + r) * 1024 + k0 + gc;
            async_copy16(ga, &As[i * 2048 + w * 512]);
            async_copy16(gb, &Bs[i * 2048 + w * 512]);
        }
        __syncthreads();

#pragma unroll
        for (int kc = 0; kc < 2; ++kc) {
            bf16x8 af[4], bf[4];
#pragma unroll
            for (int mt = 0; mt < 4; ++mt) {
                int r = abase + mt * 16 + lane15;
                af[mt] = *(const bf16x8*)&PA[r * 64 + (((kc * 4 + quad) ^ (r & 7)) << 3)];
            }
#pragma unroll
            for (int nt = 0; nt < 4; ++nt) {
                int r = bbase + nt * 16 + lane15;
                bf[nt] = *(const bf16x8*)&PB[r * 64 + (((kc * 4 + quad) ^ (r & 7)) << 3)];
            }
#pragma unroll
            for (int mt = 0; mt < 4; ++mt)
#pragma unroll
                for (int nt = 0; nt < 4; ++nt)
                    acc[mt][nt] = __builtin_amdgcn_mfma_f32_16x16x32_bf16(
                        af[mt], bf[nt], acc[mt][nt], 0, 0, 0);
        }
    }

#pragma unroll
    for (int mt = 0; mt < 4; ++mt)
#pragma unroll
        for (int nt = 0; nt < 4; ++nt) {
            if (mode == 1) {
                // rows (quad*4+reg) = feature, cols (lane15) = token
                int f0 = col0 + wc * 64 + mt * 16 + quad * 4;
                int tok = row0 + wr * 64 + nt * 16 + lane15;
                int bb = tok >> 11, ss = tok & 2047;
                int hh = f0 >> 6, dd = f0 & 63;
                u32 w0 = pack_rne(acc[mt][nt][0] * scale, acc[mt][nt][1] * scale);
                u32 w1 = pack_rne(acc[mt][nt][2] * scale, acc[mt][nt][3] * scale);
                u16* p = (u16*)Cout + (((size_t)bb * Hn + hh) * Sn + ss) * HDn + dd;
                *(uint2*)p = make_uint2(w0, w1);
            } else if (mode == 2) {
                // swapped: feature quartet consecutive -> float4 store
                int f0 = col0 + wc * 64 + mt * 16 + quad * 4;
                int tok = row0 + wr * 64 + nt * 16 + lane15;
                float4 o = make_float4(acc[mt][nt][0] * scale, acc[mt][nt][1] * scale,
                                       acc[mt][nt][2] * scale, acc[mt][nt][3] * scale);
                *(float4*)((float*)Cout + (size_t)tok * 1024 + f0) = o;
            } else {
                // mode 3 unswapped: rows = token quartet; write (B,H,HD,S)
                int n = col0 + wc * 64 + nt * 16 + lane15;
                int m0 = row0 + wr * 64 + mt * 16 + quad * 4;
                int bb = m0 >> 11, ss = m0 & 2047;
                int hh = n >> 6, dd = n & 63;
                u32 w0 = pack_rne(acc[mt][nt][0] * scale, acc[mt][nt][1] * scale);
                u32 w1 = pack_rne(acc[mt][nt][2] * scale, acc[mt][nt][3] * scale);
                u16* p = (u16*)Cout + (((size_t)bb * Hn + hh) * HDn + dd) * Sn + ss;
                *(uint2*)p = make_uint2(w0, w1);
            }
        }
}

// ---------------- flash attention, transposed-S, no-max softmax --------------
__global__ __launch_bounds__(256, 4) void attn_kernel(const u16* __restrict__ Qh,
                                                      const u16* __restrict__ Kh,
                                                      const u16* __restrict__ Vtg,
                                                      const int* __restrict__ valid_lens,
                                                      u16* __restrict__ O) {
    __shared__ alignas(16) u16 Ks[64 * 72];   // [key][d]
    __shared__ alignas(16) u16 Vt[64 * 72];   // [d][swz(key)]

    int t = threadIdx.x;
    int w = t >> 6, lane = t & 63;
    int lane15 = lane & 15, quad = lane >> 4;

    u32 raw = blockIdx.x;
    int qt = raw >> 6;
    int h = (raw >> 2) & 15;
    int b = (raw & 3) ^ ((raw >> 8) & 3);
    int bh = b * Hn + h;
    int q0 = qt * 128;
    int vl = valid_lens[b];
    int ntiles = (vl + 63) >> 6;

    const u16* Qb = Qh + (size_t)bh * (Sn * HDn);
    const u16* Kb = Kh + (size_t)bh * (Sn * HDn);
    const u16* Vb = Vtg + (size_t)bh * (HDn * Sn);

    int sr = t >> 3;
    int sc8 = (t & 7) * 8;
    int va = t & 7;
    int vcb = ((va & 4) << 3) | ((va & 1) << 4) | ((va & 2) << 1);  // key swizzle

    bf16x8 qf[2][2];
#pragma unroll
    for (int nt = 0; nt < 2; ++nt)
#pragma unroll
        for (int kc = 0; kc < 2; ++kc)
            qf[nt][kc] = *(const bf16x8*)(Qb + (size_t)(q0 + w * 32 + nt * 16 + lane15) * HDn +
                                          kc * 32 + quad * 8);

    f32x4 oacc[4][2], lacc[2];
#pragma unroll
    for (int mt = 0; mt < 4; ++mt)
#pragma unroll
        for (int nt = 0; nt < 2; ++nt)
            oacc[mt][nt] = f32x4{0.f, 0.f, 0.f, 0.f};
    lacc[0] = f32x4{0.f, 0.f, 0.f, 0.f};
    lacc[1] = f32x4{0.f, 0.f, 0.f, 0.f};

    union { u32 u[4]; bf16x8 v; } ones;
    ones.u[0] = ones.u[1] = ones.u[2] = ones.u[3] = 0x3F803F80u;

    uint4 kpre[2], vpre[2];
#pragma unroll
    for (int p = 0; p < 2; ++p) {
        kpre[p] = *(const uint4*)(Kb + (size_t)(p * 32 + sr) * HDn + sc8);
        vpre[p] = *(const uint4*)(Vb + (size_t)(p * 32 + sr) * Sn + sc8);
    }

    for (int kt = 0; kt < ntiles; ++kt) {
        int kbase = kt * 64;
        __syncthreads();
#pragma unroll
        for (int p = 0; p < 2; ++p) {
            *(uint4*)&Ks[(p * 32 + sr) * 72 + sc8] = kpre[p];
            int drow = (p * 32 + sr) * 72;
            *(uint2*)&Vt[drow + vcb] = make_uint2(vpre[p].x, vpre[p].y);
            *(uint2*)&Vt[drow + vcb + 8] = make_uint2(vpre[p].z, vpre[p].w);
        }
        __syncthreads();

        int nkb = (kt + 1 < ntiles) ? kbase + 64 : kbase;
#pragma unroll
        for (int p = 0; p < 2; ++p) {
            kpre[p] = *(const uint4*)(Kb + (size_t)(nkb + p * 32 + sr) * HDn + sc8);
            vpre[p] = *(const uint4*)(Vb + (size_t)(p * 32 + sr) * Sn + nkb + sc8);
        }

        // Sᵀ = K·Qᵀ
        f32x4 sc[4][2];
#pragma unroll
        for (int mt = 0; mt < 4; ++mt) {
            bf16x8 kf0 = *(const bf16x8*)&Ks[(mt * 16 + lane15) * 72 + quad * 8];
            bf16x8 kf1 = *(const bf16x8*)&Ks[(mt * 16 + lane15) * 72 + 32 + quad * 8];
#pragma unroll
            for (int nt = 0; nt < 2; ++nt) {
                f32x4 s = f32x4{0.f, 0.f, 0.f, 0.f};
                s = __builtin_amdgcn_mfma_f32_16x16x32_bf16(kf0, qf[nt][0], s, 0, 0, 0);
                s = __builtin_amdgcn_mfma_f32_16x16x32_bf16(kf1, qf[nt][1], s, 0, 0, 0);
                sc[mt][nt] = s;
            }
        }

        if (kbase + 64 > vl) {
#pragma unroll
            for (int mt = 0; mt < 4; ++mt)
#pragma unroll
                for (int reg = 0; reg < 4; ++reg) {
                    int key = kbase + mt * 16 + quad * 4 + reg;
                    if (key >= vl) {
                        sc[mt][0][reg] = -1e30f;
                        sc[mt][1][reg] = -1e30f;
                    }
                }
        }

#pragma unroll
        for (int mt = 0; mt < 4; ++mt)
#pragma unroll
            for (int nt = 0; nt < 2; ++nt)
#pragma unroll
                for (int reg = 0; reg < 4; ++reg)
                    sc[mt][nt][reg] = __builtin_amdgcn_exp2f(sc[mt][nt][reg]);

        union { u32 u[4]; bf16x8 v; } pv[2][2];
#pragma unroll
        for (int nt = 0; nt < 2; ++nt) {
            pv[nt][0].u[0] = pack_trunc(sc[0][nt][0], sc[0][nt][1]);
            pv[nt][0].u[1] = pack_trunc(sc[0][nt][2], sc[0][nt][3]);
            pv[nt][0].u[2] = pack_trunc(sc[1][nt][0], sc[1][nt][1]);
            pv[nt][0].u[3] = pack_trunc(sc[1][nt][2], sc[1][nt][3]);
            pv[nt][1].u[0] = pack_trunc(sc[2][nt][0], sc[2][nt][1]);
            pv[nt][1].u[1] = pack_trunc(sc[2][nt][2], sc[2][nt][3]);
            pv[nt][1].u[2] = pack_trunc(sc[3][nt][0], sc[3][nt][1]);
            pv[nt][1].u[3] = pack_trunc(sc[3][nt][2], sc[3][nt][3]);
            lacc[nt] = __builtin_amdgcn_mfma_f32_16x16x32_bf16(
                ones.v, pv[nt][0].v, lacc[nt], 0, 0, 0);
            lacc[nt] = __builtin_amdgcn_mfma_f32_16x16x32_bf16(
                ones.v, pv[nt][1].v, lacc[nt], 0, 0, 0);
        }

#pragma unroll
        for (int mt = 0; mt < 4; ++mt) {
            bf16x8 vf0 = *(const bf16x8*)&Vt[(mt * 16 + lane15) * 72 + quad * 8];
            bf16x8 vf1 = *(const bf16x8*)&Vt[(mt * 16 + lane15) * 72 + 32 + quad * 8];
#pragma unroll
            for (int nt = 0; nt < 2; ++nt) {
                oacc[mt][nt] = __builtin_amdgcn_mfma_f32_16x16x32_bf16(
                    vf0, pv[nt][0].v, oacc[mt][nt], 0, 0, 0);
                oacc[mt][nt] = __builtin_amdgcn_mfma_f32_16x16x32_bf16(
                    vf1, pv[nt][1].v, oacc[mt][nt], 0, 0, 0);
            }
        }
    }

    float rl[2];
    rl[0] = __builtin_amdgcn_rcpf(lacc[0][0]);
    rl[1] = __builtin_amdgcn_rcpf(lacc[1][0]);
#pragma unroll
    for (int mt = 0; mt < 4; ++mt)
#pragma unroll
        for (int nt = 0; nt < 2; ++nt) {
            int q = q0 + w * 32 + nt * 16 + lane15;
            int d = h * HDn + mt * 16 + quad * 4;
            u32 w0 = pack_rne(oacc[mt][nt][0] * rl[nt], oacc[mt][nt][1] * rl[nt]);
            u32 w1 = pack_rne(oacc[mt][nt][2] * rl[nt], oacc[mt][nt][3] * rl[nt]);
            *(uint2*)&O[((size_t)b * Sn + q) * Dn + d] = make_uint2(w0, w1);
        }
}

extern "C" void kernel_launch(void* const* d_in, const int* in_sizes, int n_in,
                              void* d_out, int out_size, void* d_ws, size_t ws_size,
                              hipStream_t stream) {
    const float* q  = (const float*)d_in[0];
    const float* k  = (const float*)d_in[1];
    const float* v  = (const float*)d_in[2];
    const int*   vl = (const int*)d_in[3];
    const float* Wq = (const float*)d_in[4];
    const float* Wk = (const float*)d_in[5];
    const float* Wv = (const float*)d_in[6];
    const float* Wo = (const float*)d_in[7];

    u16* ws = (u16*)d_ws;
    const size_t NE = (size_t)Bn * Sn * Dn;
    const size_t NW = (size_t)Dn * Dn;
    const float qscale = 0.125f * 1.44269504f;

    if (ws_size >= (6 * NE + 4 * NW) * 2) {
        u16* Qh  = ws;
        u16* Kh  = Qh + NE;
        u16* Vh  = Kh + NE;      // (B,H,HD,S)
        u16* Xq  = Vh + NE;
        u16* Xk  = Xq + NE;
        u16* Xv  = Xk + NE;
        u16* Wqb = Xv + NE;
        u16* Wkb = Wqb + NW;
        u16* Wvb = Wkb + NW;
        u16* Wob = Wvb + NW;
        u16* Ob  = Xq;           // reuse after projections

        CvtArgs ca;
        ca.in[0] = q;  ca.out[0] = Xq;  ca.n4[0] = (int)(NE / 4);
        ca.in[1] = k;  ca.out[1] = Xk;  ca.n4[1] = (int)(NE / 4);
        ca.in[2] = v;  ca.out[2] = Xv;  ca.n4[2] = (int)(NE / 4);
        ca.in[3] = Wq; ca.out[3] = Wqb; ca.n4[3] = (int)(NW / 4);
        ca.in[4] = Wk; ca.out[4] = Wkb; ca.n4[4] = (int)(NW / 4);
        ca.in[5] = Wv; ca.out[5] = Wvb; ca.n4[5] = (int)(NW / 4);
        ca.in[6] = Wo; ca.out[6] = Wob; ca.n4[6] = (int)(NW / 4);
        cvt_multi<<<dim3(512, 7), 256, 0, stream>>>(ca);

        GemmArgs gp;
        gp.A[0] = Xq; gp.Bw[0] = Wqb; gp.C[0] = Qh; gp.scale[0] = qscale; gp.mode[0] = 1;
        gp.A[1] = Xk; gp.Bw[1] = Wkb; gp.C[1] = Kh; gp.scale[1] = 1.0f;   gp.mode[1] = 1;
        gp.A[2] = Xv; gp.Bw[2] = Wvb; gp.C[2] = Vh; gp.scale[2] = 1.0f;   gp.mode[2] = 3;
        gemm_bf16<3><<<dim3(1536), 256, 0, stream>>>(gp);

        attn_kernel<<<dim3(1024), 256, 0, stream>>>(Qh, Kh, Vh, vl, Ob);

        GemmArgs go;
        for (int i = 0; i < 3; ++i) {
            go.A[i] = Ob; go.Bw[i] = Wob; go.C[i] = d_out;
            go.scale[i] = 1.0f; go.mode[i] = 2;
        }
        gemm_bf16<1><<<dim3(512), 256, 0, stream>>>(go);
    } else {
        u16* Qh  = ws;
        u16* Kh  = Qh + NE;
        u16* Vh  = Kh + NE;
        u16* Xb  = Vh + NE;
        u16* Wqb = Xb + NE;
        u16* Wkb = Wqb + NW;
        u16* Wvb = Wkb + NW;
        u16* Wob = Wvb + NW;
        u16* Ob  = Wob + NW;

        CvtArgs cw;
        cw.in[0] = Wq; cw.out[0] = Wqb; cw.n4[0] = (int)(NW / 4);
        cw.in[1] = Wk; cw.out[1] = Wkb; cw.n4[1] = (int)(NW / 4);
        cw.in[2] = Wv; cw.out[2] = Wvb; cw.n4[2] = (int)(NW / 4);
        cw.in[3] = Wo; cw.out[3] = Wob; cw.n4[3] = (int)(NW / 4);
        for (int i = 4; i < 7; ++i) { cw.in[i] = Wq; cw.out[i] = Wqb; cw.n4[i] = 0; }
        cvt_multi<<<dim3(512, 4), 256, 0, stream>>>(cw);

        const float* xs[3] = {q, k, v};
        u16* outs[3] = {Qh, Kh, Vh};
        const u16* wbs[3] = {Wqb, Wkb, Wvb};
        float scs[3] = {qscale, 1.0f, 1.0f};
        int mds[3] = {1, 1, 3};
        for (int i = 0; i < 3; ++i) {
            CvtArgs cx;
            cx.in[0] = xs[i]; cx.out[0] = Xb; cx.n4[0] = (int)(NE / 4);
            for (int j = 1; j < 7; ++j) { cx.in[j] = xs[i]; cx.out[j] = Xb; cx.n4[j] = 0; }
            cvt_multi<<<dim3(512, 1), 256, 0, stream>>>(cx);
            GemmArgs gp;
            for (int j = 0; j < 3; ++j) {
                gp.A[j] = Xb; gp.Bw[j] = wbs[i]; gp.C[j] = outs[i];
                gp.scale[j] = scs[i]; gp.mode[j] = mds[i];
            }
            gemm_bf16<1><<<dim3(512), 256, 0, stream>>>(gp);
        }

        attn_kernel<<<dim3(1024), 256, 0, stream>>>(Qh, Kh, Vh, vl, Ob);

        GemmArgs go;
        for (int j = 0; j < 3; ++j) {
            go.A[j] = Ob; go.Bw[j] = Wob; go.C[j] = d_out;
            go.scale[j] = 1.0f; go.mode[j] = 2;
        }
        gemm_bf16<1><<<dim3(512), 256, 0, stream>>>(go);
    }
}